// Round 7
// baseline (3443.464 us; speedup 1.0000x reference)
//
#include <hip/hip_runtime.h>
#include <hip/hip_bf16.h>

#define BB 256
#define TT 512
#define XS 40
#define HS 128
#define GS 512  // 4*HS
#define BSUB 8  // real batch rows per recurrence block (M-tile is 16, half dummy)

typedef __attribute__((ext_vector_type(8))) short bf16x8;
typedef __attribute__((ext_vector_type(4))) float f32x4;

__device__ __forceinline__ float fast_sigmoid(float x) {
    return __frcp_rn(1.0f + __expf(-x));
}
__device__ __forceinline__ float fast_tanh(float x) {
    x = fminf(fmaxf(x, -15.0f), 15.0f);
    float e = __expf(2.0f * x);
    return (e - 1.0f) * __frcp_rn(e + 1.0f);
}
__device__ __forceinline__ ushort f2bf(float f) {  // RNE float->bf16 bits
    uint u = __float_as_uint(f);
    u = u + 0x7FFFu + ((u >> 16) & 1u);
    return (ushort)(u >> 16);
}
__device__ __forceinline__ float bf2f(ushort h) {
    return __uint_as_float(((uint)h) << 16);
}

// ---- fragment-pack layout for M[R][K] (K padded to KC*32):
// elem (r,k) -> ((blkr*KC + kc)*64 + lane)*8 + e
//   blkr=r>>4, kc=k>>5, lane=(r&15)+16*((k>>3)&3), e=k&7

__global__ __launch_bounds__(256) void pack_k(
    const float* __restrict__ src, int R, int Kin, int stride, int coloff,
    int KC, ushort* __restrict__ dh, ushort* __restrict__ dl) {
    size_t p = (size_t)blockIdx.x * 256 + threadIdx.x;
    size_t total = (size_t)R * KC * 32;
    if (p >= total) return;
    int e = (int)(p & 7);
    int lane = (int)((p >> 3) & 63);
    size_t rest = p >> 9;
    int kc = (int)(rest % KC);
    int blkr = (int)(rest / KC);
    int r = blkr * 16 + (lane & 15);
    int k = kc * 32 + ((lane >> 4) & 3) * 8 + e;
    float v = (k < Kin) ? src[(size_t)r * stride + k + coloff] : 0.0f;
    ushort hb = f2bf(v);
    dh[p] = hb;
    dl[p] = f2bf(v - bf2f(hb));
}

// ---------------- gemm_mf2: B-frags register-resident, 8 row-tiles looped ----------------
// MODE 0 (proj): out fp32 [Lr*512+n], bias1+bias2, A rows remapped via Tc chunk
// MODE 2 (head2): out fp32 [Lr*128+n], relu
template <int KCA, int MODE>
__global__ __launch_bounds__(256, 2) void gemm_mf2(
    const ushort* __restrict__ Ah, const ushort* __restrict__ Al,
    const ushort* __restrict__ Bh, const ushort* __restrict__ Bl,
    const float* __restrict__ bias1, const float* __restrict__ bias2,
    float* __restrict__ outf, int t0, int TcShift, int r0, int rowtiles) {
    const int tid = threadIdx.x;
    const int w = tid >> 6, l = tid & 63;
    const int lr = l & 15, lk = l >> 4;
    const int n0 = blockIdx.y * 64;

    // B fragments once per block (per wave: all 4 n-tiles, all kc, hi+lo)
    bf16x8 rbh[4][KCA], rbl[4][KCA];
#pragma unroll
    for (int nt = 0; nt < 4; ++nt) {
        size_t nblk = (size_t)(blockIdx.y * 4 + nt);
#pragma unroll
        for (int kc = 0; kc < KCA; ++kc) {
            rbh[nt][kc] = *(const bf16x8*)(Bh + ((nblk * KCA + kc) * 64 + l) * 8);
            rbl[nt][kc] = *(const bf16x8*)(Bl + ((nblk * KCA + kc) * 64 + l) * 8);
        }
    }

    for (int rt = 0; rt < rowtiles; ++rt) {
        const int Lr0 = (blockIdx.x * rowtiles + rt) * 64 + w * 16;
        int g0;
        if (MODE == 0) {
            int b = Lr0 >> TcShift;
            g0 = Lr0 + b * (TT - (1 << TcShift)) + t0;
        } else {
            g0 = r0 + Lr0;
        }
        const size_t brg = (size_t)(g0 >> 4);

        f32x4 acc[4] = {};
#pragma unroll
        for (int kc = 0; kc < KCA; ++kc) {
            bf16x8 ahi = *(const bf16x8*)(Ah + ((brg * KCA + kc) * 64 + l) * 8);
            bf16x8 alo = *(const bf16x8*)(Al + ((brg * KCA + kc) * 64 + l) * 8);
#pragma unroll
            for (int nt = 0; nt < 4; ++nt) {
                acc[nt] = __builtin_amdgcn_mfma_f32_16x16x32_bf16(ahi, rbh[nt][kc], acc[nt], 0, 0, 0);
                acc[nt] = __builtin_amdgcn_mfma_f32_16x16x32_bf16(alo, rbh[nt][kc], acc[nt], 0, 0, 0);
                acc[nt] = __builtin_amdgcn_mfma_f32_16x16x32_bf16(ahi, rbl[nt][kc], acc[nt], 0, 0, 0);
            }
        }

#pragma unroll
        for (int nt = 0; nt < 4; ++nt) {
            int n = n0 + nt * 16 + lr;
            float bsum = bias1[n] + ((MODE == 0) ? bias2[n] : 0.0f);
#pragma unroll
            for (int e = 0; e < 4; ++e) {
                int Lr = Lr0 + 4 * lk + e;
                float v = acc[nt][e] + bsum;
                if (MODE == 0) {
                    outf[(size_t)Lr * GS + n] = v;
                } else {
                    outf[(size_t)Lr * HS + n] = fmaxf(v, 0.0f);
                }
            }
        }
    }
}

// ---------------- gemm_mf (round-6, kept for MODE 1 dual-source head1) ----------------
template <int KCA, int KCB, int MODE>
__global__ __launch_bounds__(256) void gemm_mf(
    const ushort* __restrict__ Ah, const ushort* __restrict__ Al,
    const ushort* __restrict__ Bh, const ushort* __restrict__ Bl,
    const ushort* __restrict__ A2h, const ushort* __restrict__ A2l,
    const ushort* __restrict__ B2h, const ushort* __restrict__ B2l,
    const float* __restrict__ bias1, const float* __restrict__ bias2,
    float* __restrict__ outf, ushort* __restrict__ outh, ushort* __restrict__ outl,
    int t0, int TcShift, int r0) {
    const int tid = threadIdx.x;
    const int w = tid >> 6, l = tid & 63;
    const int lr = l & 15, lk = l >> 4;
    const int Lr0 = blockIdx.x * 64 + w * 16;
    const int n0 = blockIdx.y * 64;
    const int g0 = r0 + Lr0;
    const size_t brg = (size_t)(g0 >> 4);

    f32x4 acc[4] = {};

#pragma unroll
    for (int kc = 0; kc < KCA; ++kc) {
        bf16x8 ahi = *(const bf16x8*)(Ah + ((brg * KCA + kc) * 64 + l) * 8);
        bf16x8 alo = *(const bf16x8*)(Al + ((brg * KCA + kc) * 64 + l) * 8);
#pragma unroll
        for (int nt = 0; nt < 4; ++nt) {
            size_t nblk = (size_t)(blockIdx.y * 4 + nt);
            bf16x8 bhi = *(const bf16x8*)(Bh + ((nblk * KCA + kc) * 64 + l) * 8);
            bf16x8 blo = *(const bf16x8*)(Bl + ((nblk * KCA + kc) * 64 + l) * 8);
            acc[nt] = __builtin_amdgcn_mfma_f32_16x16x32_bf16(ahi, bhi, acc[nt], 0, 0, 0);
            acc[nt] = __builtin_amdgcn_mfma_f32_16x16x32_bf16(alo, bhi, acc[nt], 0, 0, 0);
            acc[nt] = __builtin_amdgcn_mfma_f32_16x16x32_bf16(ahi, blo, acc[nt], 0, 0, 0);
        }
    }
#pragma unroll
    for (int kc = 0; kc < KCB; ++kc) {
        bf16x8 ahi = *(const bf16x8*)(A2h + ((brg * KCB + kc) * 64 + l) * 8);
        bf16x8 alo = *(const bf16x8*)(A2l + ((brg * KCB + kc) * 64 + l) * 8);
#pragma unroll
        for (int nt = 0; nt < 4; ++nt) {
            size_t nblk = (size_t)(blockIdx.y * 4 + nt);
            bf16x8 bhi = *(const bf16x8*)(B2h + ((nblk * KCB + kc) * 64 + l) * 8);
            bf16x8 blo = *(const bf16x8*)(B2l + ((nblk * KCB + kc) * 64 + l) * 8);
            acc[nt] = __builtin_amdgcn_mfma_f32_16x16x32_bf16(ahi, bhi, acc[nt], 0, 0, 0);
            acc[nt] = __builtin_amdgcn_mfma_f32_16x16x32_bf16(alo, bhi, acc[nt], 0, 0, 0);
            acc[nt] = __builtin_amdgcn_mfma_f32_16x16x32_bf16(ahi, blo, acc[nt], 0, 0, 0);
        }
    }

#pragma unroll
    for (int nt = 0; nt < 4; ++nt) {
        int n = n0 + nt * 16 + lr;
        float bsum = bias1[n];
#pragma unroll
        for (int e = 0; e < 4; ++e) {
            float v = fmaxf(acc[nt][e] + bsum, 0.0f);
            ushort hb = f2bf(v);
            ushort lb = f2bf(v - bf2f(hb));
            int blk = blockIdx.x * 4 + w;
            int kcz = n >> 5;
            int lane_p = (4 * lk + e) + 16 * ((n >> 3) & 3);
            size_t ad = ((size_t)(blk * 4 + kcz) * 64 + lane_p) * 8 + (n & 7);
            outh[ad] = hb;
            outl[ad] = lb;
        }
    }
}

// ---------------- MFMA recurrence v2: 32 blocks x 8 real rows ----------------
// Block owns batch rows [b0, b0+8). M-tile is 16 (rows 8..15 dummy/zero).
// Wave w owns gates [w*64, w*64+64). Weight frags persistent (AGPR-legal).
// Per step: acc init from xW (coalesced 64B), MFMA 3-product, raw gates -> LDS,
// phase-B per-unit activation + c/h update + packed-y store.
__global__ __launch_bounds__(512, 2) void lstm_rec7(
    const float* __restrict__ Whh, const float* __restrict__ xW,
    const float* __restrict__ h0, const float* __restrict__ c0,
    float* __restrict__ hstate, float* __restrict__ cstate,
    ushort* __restrict__ yh, ushort* __restrict__ yl, int Tc, int t0) {
    __shared__ __align__(16) ushort h_aug[16][264];  // [r][0:128]=hi,[128:256]=lo
    __shared__ float act[BSUB][516];                 // raw gate pre-activations
    const int tid = threadIdx.x;
    const int w = tid >> 6, l = tid & 63;
    const int lr = l & 15, lk = l >> 4;
    const int b0 = blockIdx.x * BSUB;
    const int gbase = w * 64;

    // persistent weight fragments (round-3-verified mapping)
    bf16x8 bhi[4][4], blo[4][4];
#pragma unroll
    for (int nt = 0; nt < 4; nt++) {
        const float* wrow = Whh + (size_t)(gbase + nt * 16 + lr) * HS;
#pragma unroll
        for (int q = 0; q < 4; q++) {
            const float4* p = (const float4*)(wrow + q * 32 + lk * 8);
            float4 v0 = p[0], v1 = p[1];
            float vv[8] = {v0.x, v0.y, v0.z, v0.w, v1.x, v1.y, v1.z, v1.w};
            bf16x8 h8, l8;
#pragma unroll
            for (int e = 0; e < 8; e++) {
                ushort hb = f2bf(vv[e]);
                h8[e] = (short)hb;
                l8[e] = (short)f2bf(vv[e] - bf2f(hb));
            }
            bhi[nt][q] = h8;
            blo[nt][q] = l8;
        }
    }

    // zero h_aug (dummy rows stay zero forever)
    for (int i = tid; i < 16 * 264; i += 512) ((ushort*)h_aug)[i] = 0;
    __syncthreads();

    // state init: thread -> unit u, rows 2*qq, 2*qq+1
    const int u = tid & 127, qq = tid >> 7;
    float c[2];
#pragma unroll
    for (int p = 0; p < 2; p++) {
        int r = 2 * qq + p;
        float hv, cv;
        if (t0 == 0) {
            hv = h0[(size_t)(b0 + r) * HS + u];
            cv = c0[(size_t)(b0 + r) * HS + u];
        } else {
            hv = hstate[(size_t)(b0 + r) * HS + u];
            cv = cstate[(size_t)(b0 + r) * HS + u];
        }
        c[p] = cv;
        ushort hb = f2bf(hv);
        h_aug[r][u] = hb;
        h_aug[r][128 + u] = f2bf(hv - bf2f(hb));
    }

    // xW row base pointers for this thread's 4 D-rows (valid when lk<2)
    const float* rowp[4];
#pragma unroll
    for (int e = 0; e < 4; e++) {
        int r = 4 * (lk & 1) + e;  // lk>=2 aliases lk-2 rows; loads skipped anyway
        rowp[e] = xW + (size_t)(b0 + r) * Tc * GS + gbase + lr;
    }

    float cur[16], nxt[16];
#pragma unroll
    for (int i = 0; i < 16; i++) cur[i] = 0.0f;
    if (lk < 2) {
#pragma unroll
        for (int nt = 0; nt < 4; nt++)
#pragma unroll
            for (int e = 0; e < 4; e++) cur[nt * 4 + e] = rowp[e][nt * 16];  // t=0
    }
    __syncthreads();

    for (int t = 0; t < Tc; ++t) {
        // depth-2 prefetch of next step's xW (coalesced 64B runs)
        int tn = (t + 1 < Tc) ? t + 1 : t;
#pragma unroll
        for (int i = 0; i < 16; i++) nxt[i] = 0.0f;
        if (lk < 2) {
            const size_t toff = (size_t)tn * GS;
#pragma unroll
            for (int nt = 0; nt < 4; nt++)
#pragma unroll
                for (int e = 0; e < 4; e++) nxt[nt * 4 + e] = rowp[e][toff + nt * 16];
        }

        // gates = xW + h.Whh^T via MFMA (3-product hi/lo split)
        f32x4 acc0 = {cur[0], cur[1], cur[2], cur[3]};
        f32x4 acc1 = {cur[4], cur[5], cur[6], cur[7]};
        f32x4 acc2 = {cur[8], cur[9], cur[10], cur[11]};
        f32x4 acc3 = {cur[12], cur[13], cur[14], cur[15]};
#pragma unroll
        for (int q = 0; q < 4; q++) {
            bf16x8 ah = *(const bf16x8*)&h_aug[lr][q * 32 + lk * 8];
            bf16x8 al = *(const bf16x8*)&h_aug[lr][128 + q * 32 + lk * 8];
            acc0 = __builtin_amdgcn_mfma_f32_16x16x32_bf16(ah, bhi[0][q], acc0, 0, 0, 0);
            acc1 = __builtin_amdgcn_mfma_f32_16x16x32_bf16(ah, bhi[1][q], acc1, 0, 0, 0);
            acc2 = __builtin_amdgcn_mfma_f32_16x16x32_bf16(ah, bhi[2][q], acc2, 0, 0, 0);
            acc3 = __builtin_amdgcn_mfma_f32_16x16x32_bf16(ah, bhi[3][q], acc3, 0, 0, 0);
            acc0 = __builtin_amdgcn_mfma_f32_16x16x32_bf16(al, bhi[0][q], acc0, 0, 0, 0);
            acc1 = __builtin_amdgcn_mfma_f32_16x16x32_bf16(al, bhi[1][q], acc1, 0, 0, 0);
            acc2 = __builtin_amdgcn_mfma_f32_16x16x32_bf16(al, bhi[2][q], acc2, 0, 0, 0);
            acc3 = __builtin_amdgcn_mfma_f32_16x16x32_bf16(al, bhi[3][q], acc3, 0, 0, 0);
            acc0 = __builtin_amdgcn_mfma_f32_16x16x32_bf16(ah, blo[0][q], acc0, 0, 0, 0);
            acc1 = __builtin_amdgcn_mfma_f32_16x16x32_bf16(ah, blo[1][q], acc1, 0, 0, 0);
            acc2 = __builtin_amdgcn_mfma_f32_16x16x32_bf16(ah, blo[2][q], acc2, 0, 0, 0);
            acc3 = __builtin_amdgcn_mfma_f32_16x16x32_bf16(ah, blo[3][q], acc3, 0, 0, 0);
        }

        // publish raw gates for real rows (0..7)
        if (lk < 2) {
#pragma unroll
            for (int e = 0; e < 4; e++) {
                int r = 4 * lk + e;
                act[r][gbase + lr] = acc0[e];
                act[r][gbase + 16 + lr] = acc1[e];
                act[r][gbase + 32 + lr] = acc2[e];
                act[r][gbase + 48 + lr] = acc3[e];
            }
        }
        __syncthreads();

        // phase B: per-unit activation, c/h update, packed-y store
#pragma unroll
        for (int p = 0; p < 2; p++) {
            int r = 2 * qq + p;
            float iv = fast_sigmoid(act[r][u]);
            float fv = fast_sigmoid(act[r][HS + u]);
            float gg = fast_tanh(act[r][2 * HS + u]);
            float ov = fast_sigmoid(act[r][3 * HS + u]);
            c[p] = fmaf(fv, c[p], iv * gg);
            float hv = ov * fast_tanh(c[p]);
            ushort hb = f2bf(hv);
            ushort lb = f2bf(hv - bf2f(hb));
            h_aug[r][u] = hb;
            h_aug[r][128 + u] = lb;
            int grow = (b0 + r) * TT + t0 + t;
            size_t ad = ((size_t)((grow >> 4) * 4 + (u >> 5)) * 64 +
                         ((grow & 15) + 16 * ((u >> 3) & 3))) * 8 + (u & 7);
            yh[ad] = hb;
            yl[ad] = lb;
            if (t == Tc - 1) {
                hstate[(size_t)(b0 + r) * HS + u] = hv;
                cstate[(size_t)(b0 + r) * HS + u] = c[p];
            }
        }
        __syncthreads();

#pragma unroll
        for (int i = 0; i < 16; i++) cur[i] = nxt[i];
    }
}

// out[row] = dot(z2[row,:], W3[0,:]) + b3 — one wave per row
__global__ __launch_bounds__(256) void head_dot(
    const float* __restrict__ z2, const float* __restrict__ W3,
    const float* __restrict__ b3, float* __restrict__ out) {
    const int wave = threadIdx.x >> 6, lane = threadIdx.x & 63;
    const int row = blockIdx.x * 4 + wave;
    const float* zr = z2 + (size_t)row * HS;
    float v = zr[lane] * W3[lane] + zr[64 + lane] * W3[64 + lane];
#pragma unroll
    for (int m = 32; m >= 1; m >>= 1) v += __shfl_xor(v, m, 64);
    if (lane == 0) out[row] = v + b3[0];
}

extern "C" void kernel_launch(void* const* d_in, const int* in_sizes, int n_in,
                              void* d_out, int out_size, void* d_ws, size_t ws_size,
                              hipStream_t stream) {
    const float* x = (const float*)d_in[0];
    const float* h0 = (const float*)d_in[1];
    const float* c0 = (const float*)d_in[2];
    const float* Wih[3] = {(const float*)d_in[3], (const float*)d_in[7], (const float*)d_in[11]};
    const float* Whh[3] = {(const float*)d_in[4], (const float*)d_in[8], (const float*)d_in[12]};
    const float* bih[3] = {(const float*)d_in[5], (const float*)d_in[9], (const float*)d_in[13]};
    const float* bhh[3] = {(const float*)d_in[6], (const float*)d_in[10], (const float*)d_in[14]};
    const float* W1 = (const float*)d_in[15];
    const float* b1 = (const float*)d_in[16];
    const float* W2 = (const float*)d_in[17];
    const float* b2 = (const float*)d_in[18];
    const float* W3 = (const float*)d_in[19];
    const float* b3 = (const float*)d_in[20];
    float* outp = (float*)d_out;

    const size_t R = (size_t)BB * TT;  // 131072 flat rows

    size_t fixed_b = R * 64 * 2 * 2
                   + R * 128 * 2 * 2
                   + (size_t)(512 * 64 + 2 * 512 * 128 + 128 * 64 + 2 * 128 * 128) * 2 * 2
                   + 2 * (size_t)BB * HS * 4 + 4096;
    int Tc = TT;
    while (Tc > 64) {
        size_t need = fixed_b + (size_t)BB * Tc * GS * 4;
        if (need <= ws_size) break;
        Tc >>= 1;
    }
    int TcShift = 31 - __builtin_clz(Tc);

    char* p = (char*)d_ws;
    float* xw = (float*)p;           p += (size_t)BB * Tc * GS * 4;
    ushort* xph = (ushort*)p;        p += R * 64 * 2;
    ushort* xpl = (ushort*)p;        p += R * 64 * 2;
    ushort* yph = (ushort*)p;        p += R * 128 * 2;
    ushort* ypl = (ushort*)p;        p += R * 128 * 2;
    ushort* w0h = (ushort*)p;        p += (size_t)512 * 64 * 2;
    ushort* w0l = (ushort*)p;        p += (size_t)512 * 64 * 2;
    ushort* w1h = (ushort*)p;        p += (size_t)512 * 128 * 2;
    ushort* w1l = (ushort*)p;        p += (size_t)512 * 128 * 2;
    ushort* w2h = (ushort*)p;        p += (size_t)512 * 128 * 2;
    ushort* w2l = (ushort*)p;        p += (size_t)512 * 128 * 2;
    ushort* w1xh = (ushort*)p;       p += (size_t)128 * 64 * 2;
    ushort* w1xl = (ushort*)p;       p += (size_t)128 * 64 * 2;
    ushort* w1yh = (ushort*)p;       p += (size_t)128 * 128 * 2;
    ushort* w1yl = (ushort*)p;       p += (size_t)128 * 128 * 2;
    ushort* w2mh = (ushort*)p;       p += (size_t)128 * 128 * 2;
    ushort* w2ml = (ushort*)p;       p += (size_t)128 * 128 * 2;
    float* hs = (float*)p;           p += (size_t)BB * HS * 4;
    float* cs = (float*)p;           p += (size_t)BB * HS * 4;

    auto packgrid = [](size_t total) { return dim3((unsigned)((total + 255) / 256)); };
    pack_k<<<packgrid(R * 64), 256, 0, stream>>>(x, (int)R, XS, XS, 0, 2, xph, xpl);
    pack_k<<<packgrid(512 * 64), 256, 0, stream>>>(Wih[0], 512, XS, XS, 0, 2, w0h, w0l);
    pack_k<<<packgrid(512 * 128), 256, 0, stream>>>(Wih[1], 512, HS, HS, 0, 4, w1h, w1l);
    pack_k<<<packgrid(512 * 128), 256, 0, stream>>>(Wih[2], 512, HS, HS, 0, 4, w2h, w2l);
    pack_k<<<packgrid(128 * 64), 256, 0, stream>>>(W1, 128, XS, XS + HS, 0, 2, w1xh, w1xl);
    pack_k<<<packgrid(128 * 128), 256, 0, stream>>>(W1, 128, HS, XS + HS, XS, 4, w1yh, w1yl);
    pack_k<<<packgrid(128 * 128), 256, 0, stream>>>(W2, 128, HS, HS, 0, 4, w2mh, w2ml);

    const ushort* wih_h[3] = {w0h, w1h, w2h};
    const ushort* wih_l[3] = {w0l, w1l, w2l};

    for (int l = 0; l < 3; ++l) {
        for (int t0 = 0; t0 < TT; t0 += Tc) {
            int tiles = BB * Tc / 64;
            int rowt = (tiles % 8 == 0) ? 8 : 1;
            dim3 gp((unsigned)(tiles / rowt), 8);
            if (l == 0)
                gemm_mf2<2, 0><<<gp, 256, 0, stream>>>(
                    xph, xpl, wih_h[0], wih_l[0], bih[0], bhh[0], xw, t0, TcShift, 0, rowt);
            else
                gemm_mf2<4, 0><<<gp, 256, 0, stream>>>(
                    yph, ypl, wih_h[l], wih_l[l], bih[l], bhh[l], xw, t0, TcShift, 0, rowt);
            lstm_rec7<<<BB / BSUB, 512, 0, stream>>>(
                Whh[l], xw, h0 + (size_t)l * BB * HS, c0 + (size_t)l * BB * HS,
                hs, cs, yph, ypl, Tc, t0);
        }
    }

    // MLP head (chunked into xw region: z1 packs + z2)
    size_t xwbytes = (size_t)BB * Tc * GS * 4;
    size_t RcMax = (xwbytes / 1024) & ~(size_t)63;
    size_t Rc = (RcMax < R) ? RcMax : R;
    for (size_t r0 = 0; r0 < R; r0 += Rc) {
        size_t rows = ((R - r0) < Rc) ? (R - r0) : Rc;
        ushort* z1h = (ushort*)xw;
        ushort* z1l = z1h + rows * 128;
        float* z2 = (float*)(z1l + rows * 128);
        dim3 gh((unsigned)(rows / 64), 2);
        gemm_mf<2, 4, 1><<<gh, 256, 0, stream>>>(
            xph, xpl, w1xh, w1xl, yph, ypl, w1yh, w1yl,
            b1, nullptr, nullptr, z1h, z1l, 0, 0, (int)r0);
        int htiles = (int)(rows / 64);
        int hrowt = (htiles % 8 == 0) ? 8 : 1;
        dim3 g2((unsigned)(htiles / hrowt), 2);
        gemm_mf2<4, 2><<<g2, 256, 0, stream>>>(
            z1h, z1l, w2mh, w2ml, b2, nullptr, z2, 0, 0, 0, hrowt);
        head_dot<<<(unsigned)(rows / 4), 256, 0, stream>>>(z2, W3, b3, outp + r0);
    }
}

// Round 8
// 2345.126 us; speedup vs baseline: 1.4683x; 1.4683x over previous
//
#include <hip/hip_runtime.h>
#include <hip/hip_bf16.h>

#define BB 256
#define TT 512
#define XS 40
#define HS 128
#define GS 512  // 4*HS

typedef __attribute__((ext_vector_type(8))) short bf16x8;
typedef __attribute__((ext_vector_type(4))) float f32x4;

__device__ __forceinline__ float fast_sigmoid(float x) {
    return __frcp_rn(1.0f + __expf(-x));
}
__device__ __forceinline__ float fast_tanh(float x) {
    x = fminf(fmaxf(x, -15.0f), 15.0f);
    float e = __expf(2.0f * x);
    return (e - 1.0f) * __frcp_rn(e + 1.0f);
}
__device__ __forceinline__ ushort f2bf(float f) {  // RNE float->bf16 bits
    uint u = __float_as_uint(f);
    u = u + 0x7FFFu + ((u >> 16) & 1u);
    return (ushort)(u >> 16);
}
__device__ __forceinline__ float bf2f(ushort h) {
    return __uint_as_float(((uint)h) << 16);
}

// ---- fragment-pack layout for M[R][K] (K padded to KC*32):
// elem (r,k) -> ((blkr*KC + kc)*64 + lane)*8 + e
//   blkr=r>>4, kc=k>>5, lane=(r&15)+16*((k>>3)&3), e=k&7

__global__ __launch_bounds__(256) void pack_k(
    const float* __restrict__ src, int R, int Kin, int stride, int coloff,
    int KC, ushort* __restrict__ dh, ushort* __restrict__ dl) {
    size_t p = (size_t)blockIdx.x * 256 + threadIdx.x;
    size_t total = (size_t)R * KC * 32;
    if (p >= total) return;
    int e = (int)(p & 7);
    int lane = (int)((p >> 3) & 63);
    size_t rest = p >> 9;
    int kc = (int)(rest % KC);
    int blkr = (int)(rest / KC);
    int r = blkr * 16 + (lane & 15);
    int k = kc * 32 + ((lane >> 4) & 3) * 8 + e;
    float v = (k < Kin) ? src[(size_t)r * stride + k + coloff] : 0.0f;
    ushort hb = f2bf(v);
    dh[p] = hb;
    dl[p] = f2bf(v - bf2f(hb));
}

// ---------------- gemm_mf2 (round-7, passing): B-frags resident, row-tiles looped ----------------
template <int KCA, int MODE>
__global__ __launch_bounds__(256, 2) void gemm_mf2(
    const ushort* __restrict__ Ah, const ushort* __restrict__ Al,
    const ushort* __restrict__ Bh, const ushort* __restrict__ Bl,
    const float* __restrict__ bias1, const float* __restrict__ bias2,
    float* __restrict__ outf, int t0, int TcShift, int r0, int rowtiles) {
    const int tid = threadIdx.x;
    const int w = tid >> 6, l = tid & 63;
    const int lr = l & 15, lk = l >> 4;
    const int n0 = blockIdx.y * 64;

    bf16x8 rbh[4][KCA], rbl[4][KCA];
#pragma unroll
    for (int nt = 0; nt < 4; ++nt) {
        size_t nblk = (size_t)(blockIdx.y * 4 + nt);
#pragma unroll
        for (int kc = 0; kc < KCA; ++kc) {
            rbh[nt][kc] = *(const bf16x8*)(Bh + ((nblk * KCA + kc) * 64 + l) * 8);
            rbl[nt][kc] = *(const bf16x8*)(Bl + ((nblk * KCA + kc) * 64 + l) * 8);
        }
    }

    for (int rt = 0; rt < rowtiles; ++rt) {
        const int Lr0 = (blockIdx.x * rowtiles + rt) * 64 + w * 16;
        int g0;
        if (MODE == 0) {
            int b = Lr0 >> TcShift;
            g0 = Lr0 + b * (TT - (1 << TcShift)) + t0;
        } else {
            g0 = r0 + Lr0;
        }
        const size_t brg = (size_t)(g0 >> 4);

        f32x4 acc[4] = {};
#pragma unroll
        for (int kc = 0; kc < KCA; ++kc) {
            bf16x8 ahi = *(const bf16x8*)(Ah + ((brg * KCA + kc) * 64 + l) * 8);
            bf16x8 alo = *(const bf16x8*)(Al + ((brg * KCA + kc) * 64 + l) * 8);
#pragma unroll
            for (int nt = 0; nt < 4; ++nt) {
                acc[nt] = __builtin_amdgcn_mfma_f32_16x16x32_bf16(ahi, rbh[nt][kc], acc[nt], 0, 0, 0);
                acc[nt] = __builtin_amdgcn_mfma_f32_16x16x32_bf16(alo, rbh[nt][kc], acc[nt], 0, 0, 0);
                acc[nt] = __builtin_amdgcn_mfma_f32_16x16x32_bf16(ahi, rbl[nt][kc], acc[nt], 0, 0, 0);
            }
        }

#pragma unroll
        for (int nt = 0; nt < 4; ++nt) {
            int n = n0 + nt * 16 + lr;
            float bsum = bias1[n] + ((MODE == 0) ? bias2[n] : 0.0f);
#pragma unroll
            for (int e = 0; e < 4; ++e) {
                int Lr = Lr0 + 4 * lk + e;
                float v = acc[nt][e] + bsum;
                if (MODE == 0) {
                    outf[(size_t)Lr * GS + n] = v;
                } else {
                    outf[(size_t)Lr * HS + n] = fmaxf(v, 0.0f);
                }
            }
        }
    }
}

// ---------------- gemm_mf (round-6/7, passing; used for dual-source head1) ----------------
template <int KCA, int KCB, int MODE>
__global__ __launch_bounds__(256) void gemm_mf(
    const ushort* __restrict__ Ah, const ushort* __restrict__ Al,
    const ushort* __restrict__ Bh, const ushort* __restrict__ Bl,
    const ushort* __restrict__ A2h, const ushort* __restrict__ A2l,
    const ushort* __restrict__ B2h, const ushort* __restrict__ B2l,
    const float* __restrict__ bias1, const float* __restrict__ bias2,
    float* __restrict__ outf, ushort* __restrict__ outh, ushort* __restrict__ outl,
    int t0, int TcShift, int r0) {
    const int tid = threadIdx.x;
    const int w = tid >> 6, l = tid & 63;
    const int lr = l & 15, lk = l >> 4;
    const int Lr0 = blockIdx.x * 64 + w * 16;
    const int n0 = blockIdx.y * 64;
    const int g0 = r0 + Lr0;
    const size_t brg = (size_t)(g0 >> 4);

    f32x4 acc[4] = {};

#pragma unroll
    for (int kc = 0; kc < KCA; ++kc) {
        bf16x8 ahi = *(const bf16x8*)(Ah + ((brg * KCA + kc) * 64 + l) * 8);
        bf16x8 alo = *(const bf16x8*)(Al + ((brg * KCA + kc) * 64 + l) * 8);
#pragma unroll
        for (int nt = 0; nt < 4; ++nt) {
            size_t nblk = (size_t)(blockIdx.y * 4 + nt);
            bf16x8 bhi = *(const bf16x8*)(Bh + ((nblk * KCA + kc) * 64 + l) * 8);
            bf16x8 blo = *(const bf16x8*)(Bl + ((nblk * KCA + kc) * 64 + l) * 8);
            acc[nt] = __builtin_amdgcn_mfma_f32_16x16x32_bf16(ahi, bhi, acc[nt], 0, 0, 0);
            acc[nt] = __builtin_amdgcn_mfma_f32_16x16x32_bf16(alo, bhi, acc[nt], 0, 0, 0);
            acc[nt] = __builtin_amdgcn_mfma_f32_16x16x32_bf16(ahi, blo, acc[nt], 0, 0, 0);
        }
    }
#pragma unroll
    for (int kc = 0; kc < KCB; ++kc) {
        bf16x8 ahi = *(const bf16x8*)(A2h + ((brg * KCB + kc) * 64 + l) * 8);
        bf16x8 alo = *(const bf16x8*)(A2l + ((brg * KCB + kc) * 64 + l) * 8);
#pragma unroll
        for (int nt = 0; nt < 4; ++nt) {
            size_t nblk = (size_t)(blockIdx.y * 4 + nt);
            bf16x8 bhi = *(const bf16x8*)(B2h + ((nblk * KCB + kc) * 64 + l) * 8);
            bf16x8 blo = *(const bf16x8*)(B2l + ((nblk * KCB + kc) * 64 + l) * 8);
            acc[nt] = __builtin_amdgcn_mfma_f32_16x16x32_bf16(ahi, bhi, acc[nt], 0, 0, 0);
            acc[nt] = __builtin_amdgcn_mfma_f32_16x16x32_bf16(alo, bhi, acc[nt], 0, 0, 0);
            acc[nt] = __builtin_amdgcn_mfma_f32_16x16x32_bf16(ahi, blo, acc[nt], 0, 0, 0);
        }
    }

#pragma unroll
    for (int nt = 0; nt < 4; ++nt) {
        int n = n0 + nt * 16 + lr;
        float bsum = bias1[n];
#pragma unroll
        for (int e = 0; e < 4; ++e) {
            float v = fmaxf(acc[nt][e] + bsum, 0.0f);
            ushort hb = f2bf(v);
            ushort lb = f2bf(v - bf2f(hb));
            int blk = blockIdx.x * 4 + w;
            int kcz = n >> 5;
            int lane_p = (4 * lk + e) + 16 * ((n >> 3) & 3);
            size_t ad = ((size_t)(blk * 4 + kcz) * 64 + lane_p) * 8 + (n & 7);
            outh[ad] = hb;
            outl[ad] = lb;
        }
    }
}

// ---------------- fused recurrence: 256 blocks (1 batch row each) ----------------
// Every 16 steps: window GEMM computes xw_win[16 timesteps][512 gates] fp32 in LDS
// (M-tile = 16 consecutive timesteps = one pack group; A = input seq pack, B = Wih
// frag pack, 3-product hi/lo). Then 16 recurrence steps: h.Whh via resident
// Whh fragments (A row 0 = real h, rows 1-15 dummy zero), acc row0 init from
// xw_win, phase-B activation + c/h update + packed-y store (in-place over input:
// window loads complete before first y-write of the window — barrier-ordered).
template <int KCIN>
__global__ __launch_bounds__(512, 2) void lstm_rec8(
    const float* __restrict__ Whh,
    const ushort* __restrict__ inh, const ushort* __restrict__ inl,
    const ushort* __restrict__ wihh, const ushort* __restrict__ wihl,
    const float* __restrict__ bih, const float* __restrict__ bhh,
    const float* __restrict__ h0, const float* __restrict__ c0,
    ushort* __restrict__ yh, ushort* __restrict__ yl) {
    __shared__ float xw_win[16][516];                // padded stride
    __shared__ __align__(16) ushort h_aug[16][264];  // [r][0:128]=hi,[128:256]=lo
    __shared__ __align__(16) float act[512];         // [u*4 + gate_type]
    const int tid = threadIdx.x;
    const int w = tid >> 6, l = tid & 63;
    const int lr = l & 15, lk = l >> 4;
    const int b = blockIdx.x;
    const int gbase = w * 64;

    // persistent Whh fragments (round-3/7-verified mapping)
    bf16x8 whh_hi[4][4], whh_lo[4][4];
#pragma unroll
    for (int nt = 0; nt < 4; nt++) {
        const float* wrow = Whh + (size_t)(gbase + nt * 16 + lr) * HS;
#pragma unroll
        for (int q = 0; q < 4; q++) {
            const float4* p = (const float4*)(wrow + q * 32 + lk * 8);
            float4 v0 = p[0], v1 = p[1];
            float vv[8] = {v0.x, v0.y, v0.z, v0.w, v1.x, v1.y, v1.z, v1.w};
            bf16x8 h8, l8;
#pragma unroll
            for (int e = 0; e < 8; e++) {
                ushort hb = f2bf(vv[e]);
                h8[e] = (short)hb;
                l8[e] = (short)f2bf(vv[e] - bf2f(hb));
            }
            whh_hi[nt][q] = h8;
            whh_lo[nt][q] = l8;
        }
    }

    for (int i = tid; i < 16 * 264; i += 512) ((ushort*)h_aug)[i] = 0;
    __syncthreads();

    const int u = tid & 127;
    float c = 0.0f;
    if (tid < 128) {
        float hv = h0[(size_t)b * HS + u];
        c = c0[(size_t)b * HS + u];
        ushort hb = f2bf(hv);
        h_aug[0][u] = hb;
        h_aug[0][128 + u] = f2bf(hv - bf2f(hb));
    }
    __syncthreads();

    for (int tw = 0; tw < TT / 16; ++tw) {
        // ---- window GEMM: xw_win[r][gate] = in[(b,16tw+r)].Wih^T + bih + bhh ----
        {
            const size_t grp = (size_t)b * (TT / 16) + tw;
            f32x4 wacc[4] = {};
#pragma unroll
            for (int kc = 0; kc < KCIN; ++kc) {
                bf16x8 ahi = *(const bf16x8*)(inh + ((grp * KCIN + kc) * 64 + l) * 8);
                bf16x8 alo = *(const bf16x8*)(inl + ((grp * KCIN + kc) * 64 + l) * 8);
#pragma unroll
                for (int nt = 0; nt < 4; ++nt) {
                    size_t nblk = (size_t)(w * 4 + nt);
                    bf16x8 whi = *(const bf16x8*)(wihh + ((nblk * KCIN + kc) * 64 + l) * 8);
                    bf16x8 wlo = *(const bf16x8*)(wihl + ((nblk * KCIN + kc) * 64 + l) * 8);
                    wacc[nt] = __builtin_amdgcn_mfma_f32_16x16x32_bf16(ahi, whi, wacc[nt], 0, 0, 0);
                    wacc[nt] = __builtin_amdgcn_mfma_f32_16x16x32_bf16(alo, whi, wacc[nt], 0, 0, 0);
                    wacc[nt] = __builtin_amdgcn_mfma_f32_16x16x32_bf16(ahi, wlo, wacc[nt], 0, 0, 0);
                }
            }
#pragma unroll
            for (int nt = 0; nt < 4; ++nt) {
                int gate = gbase + nt * 16 + lr;
                float bsum = bih[gate] + bhh[gate];
#pragma unroll
                for (int e = 0; e < 4; ++e)
                    xw_win[4 * lk + e][gate] = wacc[nt][e] + bsum;
            }
        }
        __syncthreads();

        // ---- 16 recurrence steps ----
#pragma unroll 1
        for (int tl = 0; tl < 16; ++tl) {
            float xv0 = xw_win[tl][gbase + lr];
            float xv1 = xw_win[tl][gbase + 16 + lr];
            float xv2 = xw_win[tl][gbase + 32 + lr];
            float xv3 = xw_win[tl][gbase + 48 + lr];
            f32x4 acc0 = {(lk == 0) ? xv0 : 0.0f, 0.0f, 0.0f, 0.0f};
            f32x4 acc1 = {(lk == 0) ? xv1 : 0.0f, 0.0f, 0.0f, 0.0f};
            f32x4 acc2 = {(lk == 0) ? xv2 : 0.0f, 0.0f, 0.0f, 0.0f};
            f32x4 acc3 = {(lk == 0) ? xv3 : 0.0f, 0.0f, 0.0f, 0.0f};
#pragma unroll
            for (int q = 0; q < 4; q++) {
                bf16x8 ah = *(const bf16x8*)&h_aug[lr][q * 32 + lk * 8];
                bf16x8 al = *(const bf16x8*)&h_aug[lr][128 + q * 32 + lk * 8];
                acc0 = __builtin_amdgcn_mfma_f32_16x16x32_bf16(ah, whh_hi[0][q], acc0, 0, 0, 0);
                acc1 = __builtin_amdgcn_mfma_f32_16x16x32_bf16(ah, whh_hi[1][q], acc1, 0, 0, 0);
                acc2 = __builtin_amdgcn_mfma_f32_16x16x32_bf16(ah, whh_hi[2][q], acc2, 0, 0, 0);
                acc3 = __builtin_amdgcn_mfma_f32_16x16x32_bf16(ah, whh_hi[3][q], acc3, 0, 0, 0);
                acc0 = __builtin_amdgcn_mfma_f32_16x16x32_bf16(al, whh_hi[0][q], acc0, 0, 0, 0);
                acc1 = __builtin_amdgcn_mfma_f32_16x16x32_bf16(al, whh_hi[1][q], acc1, 0, 0, 0);
                acc2 = __builtin_amdgcn_mfma_f32_16x16x32_bf16(al, whh_hi[2][q], acc2, 0, 0, 0);
                acc3 = __builtin_amdgcn_mfma_f32_16x16x32_bf16(al, whh_hi[3][q], acc3, 0, 0, 0);
                acc0 = __builtin_amdgcn_mfma_f32_16x16x32_bf16(ah, whh_lo[0][q], acc0, 0, 0, 0);
                acc1 = __builtin_amdgcn_mfma_f32_16x16x32_bf16(ah, whh_lo[1][q], acc1, 0, 0, 0);
                acc2 = __builtin_amdgcn_mfma_f32_16x16x32_bf16(ah, whh_lo[2][q], acc2, 0, 0, 0);
                acc3 = __builtin_amdgcn_mfma_f32_16x16x32_bf16(ah, whh_lo[3][q], acc3, 0, 0, 0);
            }
            if (l < 16) {
                int g0i = gbase + l;
                act[(g0i & 127) * 4 + (g0i >> 7)] = acc0[0];
                int g1i = gbase + 16 + l;
                act[(g1i & 127) * 4 + (g1i >> 7)] = acc1[0];
                int g2i = gbase + 32 + l;
                act[(g2i & 127) * 4 + (g2i >> 7)] = acc2[0];
                int g3i = gbase + 48 + l;
                act[(g3i & 127) * 4 + (g3i >> 7)] = acc3[0];
            }
            __syncthreads();
            if (tid < 128) {
                float4 g4 = *(const float4*)&act[u * 4];
                float iv = fast_sigmoid(g4.x);
                float fv = fast_sigmoid(g4.y);
                float gg = fast_tanh(g4.z);
                float ov = fast_sigmoid(g4.w);
                c = fmaf(fv, c, iv * gg);
                float hv = ov * fast_tanh(c);
                ushort hb = f2bf(hv);
                ushort lb = f2bf(hv - bf2f(hb));
                h_aug[0][u] = hb;
                h_aug[0][128 + u] = lb;
                int grow = b * TT + tw * 16 + tl;
                size_t ad = ((size_t)((grow >> 4) * 4 + (u >> 5)) * 64 +
                             ((grow & 15) + 16 * ((u >> 3) & 3))) * 8 + (u & 7);
                yh[ad] = hb;
                yl[ad] = lb;
            }
            __syncthreads();
        }
    }
}

// out[row] = dot(z2[row,:], W3[0,:]) + b3 — one wave per row
__global__ __launch_bounds__(256) void head_dot(
    const float* __restrict__ z2, const float* __restrict__ W3,
    const float* __restrict__ b3, float* __restrict__ out) {
    const int wave = threadIdx.x >> 6, lane = threadIdx.x & 63;
    const int row = blockIdx.x * 4 + wave;
    const float* zr = z2 + (size_t)row * HS;
    float v = zr[lane] * W3[lane] + zr[64 + lane] * W3[64 + lane];
#pragma unroll
    for (int m = 32; m >= 1; m >>= 1) v += __shfl_xor(v, m, 64);
    if (lane == 0) out[row] = v + b3[0];
}

extern "C" void kernel_launch(void* const* d_in, const int* in_sizes, int n_in,
                              void* d_out, int out_size, void* d_ws, size_t ws_size,
                              hipStream_t stream) {
    const float* x = (const float*)d_in[0];
    const float* h0 = (const float*)d_in[1];
    const float* c0 = (const float*)d_in[2];
    const float* Wih[3] = {(const float*)d_in[3], (const float*)d_in[7], (const float*)d_in[11]};
    const float* Whh[3] = {(const float*)d_in[4], (const float*)d_in[8], (const float*)d_in[12]};
    const float* bih[3] = {(const float*)d_in[5], (const float*)d_in[9], (const float*)d_in[13]};
    const float* bhh[3] = {(const float*)d_in[6], (const float*)d_in[10], (const float*)d_in[14]};
    const float* W1 = (const float*)d_in[15];
    const float* b1 = (const float*)d_in[16];
    const float* W2 = (const float*)d_in[17];
    const float* b2 = (const float*)d_in[18];
    const float* W3 = (const float*)d_in[19];
    const float* b3 = (const float*)d_in[20];
    float* outp = (float*)d_out;

    const size_t R = (size_t)BB * TT;  // 131072 flat rows

    char* p = (char*)d_ws;
    ushort* xph = (ushort*)p;  p += R * 64 * 2;
    ushort* xpl = (ushort*)p;  p += R * 64 * 2;
    ushort* yph = (ushort*)p;  p += R * 128 * 2;
    ushort* ypl = (ushort*)p;  p += R * 128 * 2;
    ushort* w0h = (ushort*)p;  p += (size_t)512 * 64 * 2;
    ushort* w0l = (ushort*)p;  p += (size_t)512 * 64 * 2;
    ushort* w1h = (ushort*)p;  p += (size_t)512 * 128 * 2;
    ushort* w1l = (ushort*)p;  p += (size_t)512 * 128 * 2;
    ushort* w2h = (ushort*)p;  p += (size_t)512 * 128 * 2;
    ushort* w2l = (ushort*)p;  p += (size_t)512 * 128 * 2;
    ushort* w1xh = (ushort*)p; p += (size_t)128 * 64 * 2;
    ushort* w1xl = (ushort*)p; p += (size_t)128 * 64 * 2;
    ushort* w1yh = (ushort*)p; p += (size_t)128 * 128 * 2;
    ushort* w1yl = (ushort*)p; p += (size_t)128 * 128 * 2;
    ushort* w2mh = (ushort*)p; p += (size_t)128 * 128 * 2;
    ushort* w2ml = (ushort*)p; p += (size_t)128 * 128 * 2;
    ushort* z1h = (ushort*)p;  p += R * 128 * 2;
    ushort* z1l = (ushort*)p;  p += R * 128 * 2;
    float* z2 = (float*)p;     p += R * 128 * 4;

    auto packgrid = [](size_t total) { return dim3((unsigned)((total + 255) / 256)); };
    pack_k<<<packgrid(R * 64), 256, 0, stream>>>(x, (int)R, XS, XS, 0, 2, xph, xpl);
    pack_k<<<packgrid(512 * 64), 256, 0, stream>>>(Wih[0], 512, XS, XS, 0, 2, w0h, w0l);
    pack_k<<<packgrid(512 * 128), 256, 0, stream>>>(Wih[1], 512, HS, HS, 0, 4, w1h, w1l);
    pack_k<<<packgrid(512 * 128), 256, 0, stream>>>(Wih[2], 512, HS, HS, 0, 4, w2h, w2l);
    pack_k<<<packgrid(128 * 64), 256, 0, stream>>>(W1, 128, XS, XS + HS, 0, 2, w1xh, w1xl);
    pack_k<<<packgrid(128 * 128), 256, 0, stream>>>(W1, 128, HS, XS + HS, XS, 4, w1yh, w1yl);
    pack_k<<<packgrid(128 * 128), 256, 0, stream>>>(W2, 128, HS, HS, 0, 4, w2mh, w2ml);

    // fused layers: window proj GEMM in-LDS + recurrence; y written in place
    lstm_rec8<2><<<BB, 512, 0, stream>>>(
        Whh[0], xph, xpl, w0h, w0l, bih[0], bhh[0],
        h0, c0, yph, ypl);
    lstm_rec8<4><<<BB, 512, 0, stream>>>(
        Whh[1], yph, ypl, w1h, w1l, bih[1], bhh[1],
        h0 + (size_t)BB * HS, c0 + (size_t)BB * HS, yph, ypl);
    lstm_rec8<4><<<BB, 512, 0, stream>>>(
        Whh[2], yph, ypl, w2h, w2l, bih[2], bhh[2],
        h0 + 2 * (size_t)BB * HS, c0 + 2 * (size_t)BB * HS, yph, ypl);

    // MLP head (full R, no chunking)
    dim3 gh((unsigned)(R / 64), 2);
    gemm_mf<2, 4, 1><<<gh, 256, 0, stream>>>(
        xph, xpl, w1xh, w1xl, yph, ypl, w1yh, w1yl,
        b1, nullptr, nullptr, z1h, z1l, 0, 0, 0);
    dim3 g2((unsigned)(R / 64 / 8), 2);
    gemm_mf2<4, 2><<<g2, 256, 0, stream>>>(
        z1h, z1l, w2mh, w2ml, b2, nullptr, z2, 0, 0, 0, 8);
    head_dot<<<(unsigned)(R / 4), 256, 0, stream>>>(z2, W3, b3, outp);
}